// Round 2
// baseline (9766.505 us; speedup 1.0000x reference)
//
#include <hip/hip_runtime.h>
#include <math.h>

// ---------------- problem constants ----------------
// B=64, C=256, z=15x15, x=31x31, outputs on 17x17 grid.
#define NB 64
#define NC 256

// ws float offsets
#define SB_CLS 0
#define SB_REG 3072
#define SB_BT  6144
#define SB_CT  6656
#define WS_ZB  ((size_t)8192)
#define WS_XB  (WS_ZB + (size_t)64*256*169)            // z buffer max 64*256*13*13
#define WS_RDW (WS_XB + (size_t)64*256*841)            // x buffer max 64*256*29*29
#define WS_CB  WS_XB                                   // cls tower feature reuses XB
// total ws floats = WS_RDW + 64*256*289 = 21,291,008 (~85 MB)

// d_out float offsets (x, cls, cls_dw, x_reg concatenated)
#define O_X    ((size_t)0)
#define O_CLS  ((size_t)73984)
#define O_CDW  ((size_t)92480)
#define O_XREG ((size_t)4827456)

// ---------------- BN folding ----------------
__global__ void fold_bn_k(const float* __restrict__ cg, const float* __restrict__ cb,
                          const float* __restrict__ cm, const float* __restrict__ cv,
                          const float* __restrict__ rg, const float* __restrict__ rb,
                          const float* __restrict__ rm, const float* __restrict__ rv,
                          const float* __restrict__ btg, const float* __restrict__ btb,
                          const float* __restrict__ btm, const float* __restrict__ btv,
                          const float* __restrict__ ctg, const float* __restrict__ ctb,
                          const float* __restrict__ ctm, const float* __restrict__ ctv,
                          float* __restrict__ sb)
{
    int c = threadIdx.x; // 256
    for (int i = 0; i < 6; i++) {
        float s = cg[i*256 + c] * rsqrtf(cv[i*256 + c] + 1e-5f);
        sb[SB_CLS + i*512 + c]       = s;
        sb[SB_CLS + i*512 + 256 + c] = cb[i*256 + c] - cm[i*256 + c] * s;
        float s2 = rg[i*256 + c] * rsqrtf(rv[i*256 + c] + 1e-5f);
        sb[SB_REG + i*512 + c]       = s2;
        sb[SB_REG + i*512 + 256 + c] = rb[i*256 + c] - rm[i*256 + c] * s2;
    }
    float s = btg[c] * rsqrtf(btv[c] + 1e-5f);
    sb[SB_BT + c] = s; sb[SB_BT + 256 + c] = btb[c] - btm[c] * s;
    s = ctg[c] * rsqrtf(ctv[c] + 1e-5f);
    sb[SB_CT + c] = s; sb[SB_CT + 256 + c] = ctb[c] - ctm[c] * s;
}

// ---------------- conv 3x3 (dilated, optional pad) + BN + relu ----------------
// in  [B][256][H][W], wgt [256][256][3][3], out [B][256][Ho][Wo]
// grid: (ceil(npos/(256*PPT)), 16 co-groups, B), block 256.
// Each thread: 16 co x PPT positions. Weights staged in LDS per 32-cin chunk.
template <int DH, int DW, int PAD, int PPT>
__global__ __launch_bounds__(256) void cbr_conv(
    const float* __restrict__ in, const float* __restrict__ wgt,
    const float* __restrict__ sb, float* __restrict__ out,
    int H, int W, int Ho, int Wo)
{
    const int tid = threadIdx.x;
    const int b = blockIdx.z, cog = blockIdx.y;
    const int npos = Ho * Wo;
    const int pbase = blockIdx.x * (256 * PPT) + tid;

    int ohs[PPT], ows[PPT];
    bool act[PPT];
#pragma unroll
    for (int q = 0; q < PPT; q++) {
        int p = pbase + q * 256;
        act[q] = p < npos;
        int pp = act[q] ? p : 0;
        ohs[q] = pp / Wo; ows[q] = pp % Wo;
    }

    float acc[PPT][16];
#pragma unroll
    for (int q = 0; q < PPT; q++)
#pragma unroll
        for (int j = 0; j < 16; j++) acc[q][j] = 0.0f;

    __shared__ __align__(16) float wlds[32][9][16]; // [ci][k][coj]
    const size_t HW = (size_t)H * W;
    const float* inb = in + (size_t)b * 256 * HW;

    for (int c0 = 0; c0 < 256; c0 += 32) {
        __syncthreads();
#pragma unroll 1
        for (int i = tid; i < 32 * 9 * 16; i += 256) {
            int coj = i / 288, r = i % 288;
            wlds[r / 9][r % 9][coj] =
                wgt[(size_t)(cog * 16 + coj) * 2304 + (size_t)c0 * 9 + r];
        }
        __syncthreads();
#pragma unroll 1
        for (int ci = 0; ci < 32; ci++) {
            const float* ip = inb + (size_t)(c0 + ci) * HW;
            float iv[PPT][9];
#pragma unroll
            for (int q = 0; q < PPT; q++) {
#pragma unroll
                for (int kh = 0; kh < 3; kh++) {
                    int ih = ohs[q] - PAD + kh * DH;
                    int ihc = PAD ? (ih < 0 ? 0 : (ih >= H ? H - 1 : ih)) : ih;
                    bool okh = PAD ? ((unsigned)ih < (unsigned)H) : true;
#pragma unroll
                    for (int kw = 0; kw < 3; kw++) {
                        int iw = ows[q] - PAD + kw * DW;
                        int iwc = PAD ? (iw < 0 ? 0 : (iw >= W ? W - 1 : iw)) : iw;
                        bool ok = act[q] && okh &&
                                  (PAD ? ((unsigned)iw < (unsigned)W) : true);
                        float v = ip[(size_t)ihc * W + iwc];
                        iv[q][kh * 3 + kw] = ok ? v : 0.0f;
                    }
                }
            }
#pragma unroll
            for (int k = 0; k < 9; k++) {
                float wv[16];
                const float4* wr = (const float4*)(&wlds[ci][k][0]);
                ((float4*)wv)[0] = wr[0]; ((float4*)wv)[1] = wr[1];
                ((float4*)wv)[2] = wr[2]; ((float4*)wv)[3] = wr[3];
#pragma unroll
                for (int q = 0; q < PPT; q++) {
                    float v = iv[q][k];
#pragma unroll
                    for (int j = 0; j < 16; j++)
                        acc[q][j] = fmaf(v, wv[j], acc[q][j]);
                }
            }
        }
    }

    float scl[16], bia[16];
#pragma unroll
    for (int j = 0; j < 16; j++) {
        scl[j] = sb[cog * 16 + j];
        bia[j] = sb[256 + cog * 16 + j];
    }
#pragma unroll
    for (int q = 0; q < PPT; q++) {
        if (!act[q]) continue;
        int p = pbase + q * 256;
        size_t ob = ((size_t)b * 256 + cog * 16) * npos + p;
#pragma unroll
        for (int j = 0; j < 16; j++) {
            float v = fmaf(acc[q][j], scl[j], bia[j]);
            out[ob + (size_t)j * npos] = v > 0.0f ? v : 0.0f;
        }
    }
}

// ---------------- depthwise xcorr (one of 3), softmax-weighted accumulate ----------------
// z [B*C][HZ_][WZ_], x [B*C][16+HZ_][WX_], out [B*C][17][17]
template <int HZ_, int WZ_, int WX_, int IDX>
__global__ __launch_bounds__(192) void xcorr_one(
    const float* __restrict__ z, const float* __restrict__ x,
    const float* __restrict__ w3, float* __restrict__ out)
{
    constexpr int HX_ = 16 + HZ_;
    constexpr int NX = HX_ * WX_;
    constexpr int NZ = HZ_ * WZ_;
    __shared__ float xs[NX + 4];
    __shared__ float zs[NZ];
    const int bc = blockIdx.x;
    const float* xp = x + (size_t)bc * NX;
    const float* zp = z + (size_t)bc * NZ;
    for (int i = threadIdx.x; i < NX; i += 192) xs[i] = xp[i];
    for (int i = threadIdx.x; i < NZ; i += 192) zs[i] = zp[i];

    float a = w3[0], b = w3[1], c = w3[2];
    float mx = fmaxf(a, fmaxf(b, c));
    float e0 = expf(a - mx), e1 = expf(b - mx), e2 = expf(c - mx);
    float wt = (IDX == 0 ? e0 : (IDX == 1 ? e1 : e2)) / (e0 + e1 + e2);
    __syncthreads();

    int t = threadIdx.x;
    if (t >= 153) return;
    int oh = t / 9, owp = t % 9, ow0 = owp * 2;
    float s0 = 0.0f, s1 = 0.0f;
#pragma unroll 1
    for (int kh = 0; kh < HZ_; kh++) {
        const float* xr = &xs[(oh + kh) * WX_ + ow0];
        const float* zr = &zs[kh * WZ_];
#pragma unroll
        for (int kw = 0; kw < WZ_; kw++) {
            float zv = zr[kw];
            s0 = fmaf(xr[kw], zv, s0);
            s1 = fmaf(xr[kw + 1], zv, s1);
        }
    }
    size_t o = (size_t)bc * 289 + oh * 17 + ow0;
    if (IDX == 0) {
        out[o] = wt * s0;
        if (owp < 8) out[o + 1] = wt * s1;
    } else {
        out[o] += wt * s0;
        if (owp < 8) out[o + 1] += wt * s1;
    }
}

// ---------------- bbox pred: conv 3x3 pad1 C->4, + bpb, exp(min(adj*bp+bias,4.7)) ----------------
__global__ __launch_bounds__(320) void bp_pred(
    const float* __restrict__ xr, const float* __restrict__ w,
    const float* __restrict__ wb, const float* __restrict__ adj,
    const float* __restrict__ bia, float* __restrict__ outx)
{
    int b = blockIdx.x;
    int p = threadIdx.x;
    if (p >= 289) return;
    int oh = p / 17, ow = p % 17;
    float acc[4] = {0.f, 0.f, 0.f, 0.f};
    const float* xb = xr + (size_t)b * 256 * 289;
#pragma unroll 1
    for (int cin = 0; cin < 256; cin++) {
        const float* ip = xb + (size_t)cin * 289;
#pragma unroll
        for (int kh = 0; kh < 3; kh++) {
            int ih = oh - 1 + kh;
            bool okh = (unsigned)ih < 17u;
            int ihc = okh ? ih : 0;
#pragma unroll
            for (int kw = 0; kw < 3; kw++) {
                int iw = ow - 1 + kw;
                bool ok = okh && ((unsigned)iw < 17u);
                int iwc = ok ? iw : 0;
                float v = ip[ihc * 17 + iwc];
                v = ok ? v : 0.0f;
#pragma unroll
                for (int co = 0; co < 4; co++)
                    acc[co] = fmaf(v, w[(size_t)(co * 256 + cin) * 9 + kh * 3 + kw], acc[co]);
            }
        }
    }
    float ad = adj[0];
#pragma unroll
    for (int co = 0; co < 4; co++) {
        float t = fmaf(ad, acc[co] + wb[co], bia[co]);
        outx[((size_t)b * 4 + co) * 289 + p] = expf(fminf(t, 4.7f));
    }
}

// ---------------- cls pred: conv 3x3 pad1 C->1, 0.1*(conv+cpb) ----------------
__global__ __launch_bounds__(320) void cp_pred(
    const float* __restrict__ cfeat, const float* __restrict__ w,
    const float* __restrict__ wb, float* __restrict__ outc)
{
    int b = blockIdx.x;
    int p = threadIdx.x;
    if (p >= 289) return;
    int oh = p / 17, ow = p % 17;
    float acc = 0.f;
#pragma unroll 1
    for (int cin = 0; cin < 256; cin++) {
        const float* ip = cfeat + ((size_t)b * 256 + cin) * 289;
#pragma unroll
        for (int kh = 0; kh < 3; kh++) {
            int ih = oh - 1 + kh;
            bool okh = (unsigned)ih < 17u;
            int ihc = okh ? ih : 0;
#pragma unroll
            for (int kw = 0; kw < 3; kw++) {
                int iw = ow - 1 + kw;
                bool ok = okh && ((unsigned)iw < 17u);
                int iwc = ok ? iw : 0;
                float v = ip[ihc * 17 + iwc];
                v = ok ? v : 0.0f;
                acc = fmaf(v, w[(size_t)cin * 9 + kh * 3 + kw], acc);
            }
        }
    }
    outc[(size_t)b * 289 + p] = 0.1f * (acc + wb[0]);
}

// ---------------- host launch ----------------
extern "C" void kernel_launch(void* const* d_in, const int* in_sizes, int n_in,
                              void* d_out, int out_size, void* d_ws, size_t ws_size,
                              hipStream_t stream)
{
    (void)in_sizes; (void)n_in; (void)out_size; (void)ws_size;
    const float* search = (const float*)d_in[0];
    const float* kern   = (const float*)d_in[1];
    const float* cls_mw = (const float*)d_in[2];
    const float* reg_mw = (const float*)d_in[7];
    const float* cls_dww = (const float*)d_in[12];
    const float* reg_dww = (const float*)d_in[13];
    const float* btw = (const float*)d_in[14];
    const float* ctw = (const float*)d_in[19];
    const float* bpw = (const float*)d_in[24];
    const float* bpb = (const float*)d_in[25];
    const float* cpw = (const float*)d_in[26];
    const float* cpb = (const float*)d_in[27];
    const float* adj = (const float*)d_in[28];
    const float* bia = (const float*)d_in[29];

    float* ws  = (float*)d_ws;
    float* out = (float*)d_out;

    fold_bn_k<<<1, 256, 0, stream>>>(
        (const float*)d_in[3], (const float*)d_in[4], (const float*)d_in[5], (const float*)d_in[6],
        (const float*)d_in[8], (const float*)d_in[9], (const float*)d_in[10], (const float*)d_in[11],
        (const float*)d_in[15], (const float*)d_in[16], (const float*)d_in[17], (const float*)d_in[18],
        (const float*)d_in[20], (const float*)d_in[21], (const float*)d_in[22], (const float*)d_in[23],
        ws);

    const size_t W6 = (size_t)256 * 256 * 9; // per-conv weight stride in mw[6]

    auto branch = [&](const float* mw, const float* sbb, const float* dww, float* dwout) {
        // pair 0: dil (1,1): z 13x13, x 29x29
        cbr_conv<1, 1, 0, 1><<<dim3(1, 16, 64), 256, 0, stream>>>(
            kern, mw + 0 * W6, sbb + 0 * 512, ws + WS_ZB, 15, 15, 13, 13);
        cbr_conv<1, 1, 0, 2><<<dim3(2, 16, 64), 256, 0, stream>>>(
            search, mw + 1 * W6, sbb + 1 * 512, ws + WS_XB, 31, 31, 29, 29);
        xcorr_one<13, 13, 29, 0><<<16384, 192, 0, stream>>>(ws + WS_ZB, ws + WS_XB, dww, dwout);
        // pair 1: dil (2,1): z 11x13, x 27x29
        cbr_conv<2, 1, 0, 1><<<dim3(1, 16, 64), 256, 0, stream>>>(
            kern, mw + 2 * W6, sbb + 2 * 512, ws + WS_ZB, 15, 15, 11, 13);
        cbr_conv<2, 1, 0, 2><<<dim3(2, 16, 64), 256, 0, stream>>>(
            search, mw + 3 * W6, sbb + 3 * 512, ws + WS_XB, 31, 31, 27, 29);
        xcorr_one<11, 13, 29, 1><<<16384, 192, 0, stream>>>(ws + WS_ZB, ws + WS_XB, dww, dwout);
        // pair 2: dil (1,2): z 13x11, x 29x27
        cbr_conv<1, 2, 0, 1><<<dim3(1, 16, 64), 256, 0, stream>>>(
            kern, mw + 4 * W6, sbb + 4 * 512, ws + WS_ZB, 15, 15, 13, 11);
        cbr_conv<1, 2, 0, 2><<<dim3(2, 16, 64), 256, 0, stream>>>(
            search, mw + 5 * W6, sbb + 5 * 512, ws + WS_XB, 31, 31, 29, 27);
        xcorr_one<13, 11, 27, 2><<<16384, 192, 0, stream>>>(ws + WS_ZB, ws + WS_XB, dww, dwout);
    };

    // cls branch -> cls_dw directly in d_out; reg branch -> ws
    branch(cls_mw, ws + SB_CLS, cls_dww, out + O_CDW);
    branch(reg_mw, ws + SB_REG, reg_dww, ws + WS_RDW);

    // bbox tower: CBR(reg_dw) -> x_reg (d_out), then bp conv + exp -> x (d_out)
    cbr_conv<1, 1, 1, 1><<<dim3(2, 16, 64), 256, 0, stream>>>(
        ws + WS_RDW, btw, ws + SB_BT, out + O_XREG, 17, 17, 17, 17);
    bp_pred<<<64, 320, 0, stream>>>(out + O_XREG, bpw, bpb, adj, bia, out + O_X);

    // cls tower: CBR(cls_dw) -> c (ws), then cp conv -> cls (d_out)
    cbr_conv<1, 1, 1, 1><<<dim3(2, 16, 64), 256, 0, stream>>>(
        out + O_CDW, ctw, ws + SB_CT, ws + WS_CB, 17, 17, 17, 17);
    cp_pred<<<64, 320, 0, stream>>>(ws + WS_CB, cpw, cpb, out + O_CLS);
}

// Round 3
// 4680.448 us; speedup vs baseline: 2.0867x; 2.0867x over previous
//
#include <hip/hip_runtime.h>
#include <math.h>

typedef unsigned short ushortT;
typedef unsigned int uintT;

using bf8   = __attribute__((ext_vector_type(8))) short;
using f32x4 = __attribute__((ext_vector_type(4))) float;

// ---------------- problem constants ----------------
// B=64, C=256, z=15x15, x=31x31, outputs on 17x17 grid.

// ws float offsets
#define SB_CLS 0
#define SB_REG 3072
#define SB_BT  6144
#define SB_CT  6656
#define WT_HI   ((size_t)8192)
#define WT_LO   (WT_HI + (size_t)1769472)
#define INT_SH  (WT_LO + (size_t)1769472)
#define INT_SL  (INT_SH + (size_t)7872512)
#define INT_ZH  (INT_SL + (size_t)7872512)
#define INT_ZL  (INT_ZH + (size_t)1843200)
#define WS_ZB   (INT_ZL + (size_t)1843200)              // f32 64*256*169
#define WS_XB   (WS_ZB + (size_t)2768896)               // f32 64*256*841
#define WS_RDW  (WS_XB + (size_t)13778944)              // f32 64*256*289
#define WS_CB   WS_XB                                   // cls tower feature reuses XB
// total ws floats = WS_RDW + 4734976 = 44,261,376 (~177 MB)

// d_out float offsets (x, cls, cls_dw, x_reg concatenated)
#define O_X    ((size_t)0)
#define O_CLS  ((size_t)73984)
#define O_CDW  ((size_t)92480)
#define O_XREG ((size_t)4827456)

// ---------------- helpers ----------------
__device__ __forceinline__ ushortT f2bf(float v) {
    uintT u = __float_as_uint(v);
    uintT r = ((u >> 16) & 1u) + 0x7fffu;   // round-to-nearest-even
    return (ushortT)((u + r) >> 16);
}
__device__ __forceinline__ float bf2f(ushortT h) {
    return __uint_as_float(((uintT)h) << 16);
}
__device__ __forceinline__ void gl16(const ushortT* g, ushortT* l) {
    __builtin_amdgcn_global_load_lds(
        (const __attribute__((address_space(1))) void*)g,
        (__attribute__((address_space(3))) void*)l, 16, 0, 0);
}

// ---------------- BN folding ----------------
__global__ void fold_bn_k(const float* __restrict__ cg, const float* __restrict__ cb,
                          const float* __restrict__ cm, const float* __restrict__ cv,
                          const float* __restrict__ rg, const float* __restrict__ rb,
                          const float* __restrict__ rm, const float* __restrict__ rv,
                          const float* __restrict__ btg, const float* __restrict__ btb,
                          const float* __restrict__ btm, const float* __restrict__ btv,
                          const float* __restrict__ ctg, const float* __restrict__ ctb,
                          const float* __restrict__ ctm, const float* __restrict__ ctv,
                          float* __restrict__ sb)
{
    int c = threadIdx.x; // 256
    for (int i = 0; i < 6; i++) {
        float s = cg[i*256 + c] * rsqrtf(cv[i*256 + c] + 1e-5f);
        sb[SB_CLS + i*512 + c]       = s;
        sb[SB_CLS + i*512 + 256 + c] = cb[i*256 + c] - cm[i*256 + c] * s;
        float s2 = rg[i*256 + c] * rsqrtf(rv[i*256 + c] + 1e-5f);
        sb[SB_REG + i*512 + c]       = s2;
        sb[SB_REG + i*512 + 256 + c] = rb[i*256 + c] - rm[i*256 + c] * s2;
    }
    float s = btg[c] * rsqrtf(btv[c] + 1e-5f);
    sb[SB_BT + c] = s; sb[SB_BT + 256 + c] = btb[c] - btm[c] * s;
    s = ctg[c] * rsqrtf(ctv[c] + 1e-5f);
    sb[SB_CT + c] = s; sb[SB_CT + 256 + c] = ctb[c] - ctm[c] * s;
}

// ---------------- NCHW f32 -> NHWC bf16 hi/lo planes ----------------
// grid (ceil(HW/32), 8, B), block (32,8)
__global__ __launch_bounds__(256) void nchw2nhwc_split(
    const float* __restrict__ in, ushortT* __restrict__ hi, ushortT* __restrict__ lo, int HW)
{
    __shared__ float t[32][33];
    const int b = blockIdx.z, ci0 = blockIdx.y * 32, p0 = blockIdx.x * 32;
    const int tx = threadIdx.x, ty = threadIdx.y;
    for (int i = 0; i < 32; i += 8) {
        int ci = ci0 + ty + i, p = p0 + tx;
        t[ty + i][tx] = (p < HW) ? in[((size_t)(b * 256 + ci)) * HW + p] : 0.0f;
    }
    __syncthreads();
    for (int i = 0; i < 32; i += 8) {
        int p = p0 + ty + i;
        if (p < HW) {
            float v = t[tx][ty + i];
            ushortT h = f2bf(v);
            ushortT l = f2bf(v - bf2f(h));
            size_t o = ((size_t)b * HW + p) * 256 + ci0 + tx;
            hi[o] = h; lo[o] = l;
        }
    }
}

// ---------------- weight transform: [co][ci][9] -> [co][kidx*256+ci] hi/lo ----------------
// grid 6*256 blocks (conv, co), block 256
__global__ __launch_bounds__(256) void wt_split(
    const float* __restrict__ w, ushortT* __restrict__ whi, ushortT* __restrict__ wlo)
{
    const int co = blockIdx.x & 255, conv = blockIdx.x >> 8;
    const float* src = w + ((size_t)conv * 256 + co) * 2304;
    __shared__ float lw[2304];
    const int t = threadIdx.x;
#pragma unroll
    for (int i = 0; i < 9; i++) lw[i * 256 + t] = src[i * 256 + t];
    __syncthreads();
    size_t ob = ((size_t)conv * 256 + co) * 2304;
#pragma unroll
    for (int i = 0; i < 9; i++) {
        float v = lw[t * 9 + i];
        ushortT h = f2bf(v);
        whi[ob + i * 256 + t] = h;
        wlo[ob + i * 256 + t] = f2bf(v - bf2f(h));
    }
}

// ---------------- MFMA implicit-GEMM conv (VALID, dilated) + BN + relu ----------------
// A: in_t NHWC bf16 hi/lo [B][HI][WI][256]; B: wt [co][kidx*256+ci] hi/lo
// out f32 NCHW [B][256][Ho*Wo]. grid (ceil(npos/128), 2, B), block 256 (4 waves).
// Split-bf16: acc += Ahi*Bhi + Ahi*Blo + Alo*Bhi  (near-f32 accuracy).
template <int DH, int DW, int Ho, int Wo, int HI, int WI>
__global__ __launch_bounds__(256, 2) void mfma_conv(
    const ushortT* __restrict__ ahi, const ushortT* __restrict__ alo,
    const ushortT* __restrict__ whi, const ushortT* __restrict__ wlo,
    const float* __restrict__ sb, float* __restrict__ out)
{
    constexpr int NPOS = Ho * Wo;
    __shared__ __align__(16) ushortT lds[4][4096];   // planes: A_hi, A_lo, B_hi, B_lo ([128][32])

    const int t = threadIdx.x, lane = t & 63, wave = t >> 6;
    const int b = blockIdx.z, cog = blockIdx.y;
    const int m0 = blockIdx.x * 128;
    const int wrow = wave >> 1, wcol = wave & 1;

    // staging assignment: instr q in {0,1}; row = q*64 + wave*16 + (lane>>2); 16B chunk (lane&3)
    const int row0 = wave * 16 + (lane >> 2);
    const int row1 = 64 + row0;
    const int e0 = (lane & 3) * 8;                   // ushort offset within 32-elem k-run
    int p0 = m0 + row0; if (p0 > NPOS - 1) p0 = NPOS - 1;
    int p1 = m0 + row1; if (p1 > NPOS - 1) p1 = NPOS - 1;
    const int oh0 = p0 / Wo, ow0 = p0 - oh0 * Wo;
    const int oh1 = p1 / Wo, ow1 = p1 - oh1 * Wo;
    const size_t wb0 = (size_t)(cog * 128 + row0) * 2304 + e0;
    const size_t wb1 = (size_t)(cog * 128 + row1) * 2304 + e0;

    const int dq0 = wave * 16 * 32;                  // LDS ushort offset, q=0 (wave-uniform)
    const int dq1 = (64 + wave * 16) * 32;           // q=1

    f32x4 acc[4][4];
#pragma unroll
    for (int i = 0; i < 4; i++)
#pragma unroll
        for (int j = 0; j < 4; j++) acc[i][j] = (f32x4){0.f, 0.f, 0.f, 0.f};

    const int arow = lane & 15, koff = (lane >> 4) * 8;

#pragma unroll 1
    for (int kidx = 0; kidx < 9; ++kidx) {
        const int kh = kidx / 3, kw = kidx - kh * 3;
        const size_t ab0 = ((size_t)((b * HI) + oh0 + DH * kh) * WI + ow0 + DW * kw) * 256 + e0;
        const size_t ab1 = ((size_t)((b * HI) + oh1 + DH * kh) * WI + ow1 + DW * kw) * 256 + e0;
        const size_t wk = (size_t)kidx * 256;
#pragma unroll 1
        for (int s = 0; s < 8; ++s) {
            const int cs = s * 32;
            gl16(ahi + ab0 + cs, &lds[0][dq0]);
            gl16(ahi + ab1 + cs, &lds[0][dq1]);
            gl16(alo + ab0 + cs, &lds[1][dq0]);
            gl16(alo + ab1 + cs, &lds[1][dq1]);
            gl16(whi + wb0 + wk + cs, &lds[2][dq0]);
            gl16(whi + wb1 + wk + cs, &lds[2][dq1]);
            gl16(wlo + wb0 + wk + cs, &lds[3][dq0]);
            gl16(wlo + wb1 + wk + cs, &lds[3][dq1]);
            __syncthreads();

            bf8 ah[4], al[4], bh[4], bl[4];
#pragma unroll
            for (int mt = 0; mt < 4; ++mt) {
                int r = wrow * 64 + mt * 16 + arow;
                ah[mt] = *(const bf8*)&lds[0][r * 32 + koff];
                al[mt] = *(const bf8*)&lds[1][r * 32 + koff];
            }
#pragma unroll
            for (int nt = 0; nt < 4; ++nt) {
                int r = wcol * 64 + nt * 16 + arow;
                bh[nt] = *(const bf8*)&lds[2][r * 32 + koff];
                bl[nt] = *(const bf8*)&lds[3][r * 32 + koff];
            }
#pragma unroll
            for (int mt = 0; mt < 4; ++mt)
#pragma unroll
                for (int nt = 0; nt < 4; ++nt) {
                    acc[mt][nt] = __builtin_amdgcn_mfma_f32_16x16x32_bf16(ah[mt], bh[nt], acc[mt][nt], 0, 0, 0);
                    acc[mt][nt] = __builtin_amdgcn_mfma_f32_16x16x32_bf16(ah[mt], bl[nt], acc[mt][nt], 0, 0, 0);
                    acc[mt][nt] = __builtin_amdgcn_mfma_f32_16x16x32_bf16(al[mt], bh[nt], acc[mt][nt], 0, 0, 0);
                }
            __syncthreads();
        }
    }

    // epilogue: folded BN + relu, f32 NCHW store
#pragma unroll
    for (int nt = 0; nt < 4; ++nt) {
        const int co = cog * 128 + wcol * 64 + nt * 16 + arow;
        const float scl = sb[co], bia = sb[256 + co];
        const size_t ob = ((size_t)b * 256 + co) * NPOS;
#pragma unroll
        for (int mt = 0; mt < 4; ++mt)
#pragma unroll
            for (int r = 0; r < 4; ++r) {
                int p = m0 + wrow * 64 + mt * 16 + (lane >> 4) * 4 + r;
                if (p < NPOS) {
                    float v = fmaf(acc[mt][nt][r], scl, bia);
                    out[ob + p] = v > 0.f ? v : 0.f;
                }
            }
    }
}

// ---------------- f32 conv 3x3 pad1 + BN + relu (towers; verified round-0) ----------------
template <int DH, int DW, int PAD, int PPT>
__global__ __launch_bounds__(256) void cbr_conv(
    const float* __restrict__ in, const float* __restrict__ wgt,
    const float* __restrict__ sb, float* __restrict__ out,
    int H, int W, int Ho, int Wo)
{
    const int tid = threadIdx.x;
    const int b = blockIdx.z, cog = blockIdx.y;
    const int npos = Ho * Wo;
    const int pbase = blockIdx.x * (256 * PPT) + tid;

    int ohs[PPT], ows[PPT];
    bool act[PPT];
#pragma unroll
    for (int q = 0; q < PPT; q++) {
        int p = pbase + q * 256;
        act[q] = p < npos;
        int pp = act[q] ? p : 0;
        ohs[q] = pp / Wo; ows[q] = pp % Wo;
    }

    float acc[PPT][16];
#pragma unroll
    for (int q = 0; q < PPT; q++)
#pragma unroll
        for (int j = 0; j < 16; j++) acc[q][j] = 0.0f;

    __shared__ __align__(16) float wlds[32][9][16];
    const size_t HW = (size_t)H * W;
    const float* inb = in + (size_t)b * 256 * HW;

    for (int c0 = 0; c0 < 256; c0 += 32) {
        __syncthreads();
#pragma unroll 1
        for (int i = tid; i < 32 * 9 * 16; i += 256) {
            int coj = i / 288, r = i % 288;
            wlds[r / 9][r % 9][coj] =
                wgt[(size_t)(cog * 16 + coj) * 2304 + (size_t)c0 * 9 + r];
        }
        __syncthreads();
#pragma unroll 1
        for (int ci = 0; ci < 32; ci++) {
            const float* ip = inb + (size_t)(c0 + ci) * HW;
            float iv[PPT][9];
#pragma unroll
            for (int q = 0; q < PPT; q++) {
#pragma unroll
                for (int kh = 0; kh < 3; kh++) {
                    int ih = ohs[q] - PAD + kh * DH;
                    int ihc = PAD ? (ih < 0 ? 0 : (ih >= H ? H - 1 : ih)) : ih;
                    bool okh = PAD ? ((unsigned)ih < (unsigned)H) : true;
#pragma unroll
                    for (int kw = 0; kw < 3; kw++) {
                        int iw = ows[q] - PAD + kw * DW;
                        int iwc = PAD ? (iw < 0 ? 0 : (iw >= W ? W - 1 : iw)) : iw;
                        bool ok = act[q] && okh &&
                                  (PAD ? ((unsigned)iw < (unsigned)W) : true);
                        float v = ip[(size_t)ihc * W + iwc];
                        iv[q][kh * 3 + kw] = ok ? v : 0.0f;
                    }
                }
            }
#pragma unroll
            for (int k = 0; k < 9; k++) {
                float wv[16];
                const float4* wr = (const float4*)(&wlds[ci][k][0]);
                ((float4*)wv)[0] = wr[0]; ((float4*)wv)[1] = wr[1];
                ((float4*)wv)[2] = wr[2]; ((float4*)wv)[3] = wr[3];
#pragma unroll
                for (int q = 0; q < PPT; q++) {
                    float v = iv[q][k];
#pragma unroll
                    for (int j = 0; j < 16; j++)
                        acc[q][j] = fmaf(v, wv[j], acc[q][j]);
                }
            }
        }
    }

    float scl[16], bia[16];
#pragma unroll
    for (int j = 0; j < 16; j++) {
        scl[j] = sb[cog * 16 + j];
        bia[j] = sb[256 + cog * 16 + j];
    }
#pragma unroll
    for (int q = 0; q < PPT; q++) {
        if (!act[q]) continue;
        int p = pbase + q * 256;
        size_t ob = ((size_t)b * 256 + cog * 16) * npos + p;
#pragma unroll
        for (int j = 0; j < 16; j++) {
            float v = fmaf(acc[q][j], scl[j], bia[j]);
            out[ob + (size_t)j * npos] = v > 0.0f ? v : 0.0f;
        }
    }
}

// ---------------- depthwise xcorr (one of 3), softmax-weighted accumulate ----------------
template <int HZ_, int WZ_, int WX_, int IDX>
__global__ __launch_bounds__(192) void xcorr_one(
    const float* __restrict__ z, const float* __restrict__ x,
    const float* __restrict__ w3, float* __restrict__ out)
{
    constexpr int HX_ = 16 + HZ_;
    constexpr int NX = HX_ * WX_;
    constexpr int NZ = HZ_ * WZ_;
    __shared__ float xs[NX + 4];
    __shared__ float zs[NZ];
    const int bc = blockIdx.x;
    const float* xp = x + (size_t)bc * NX;
    const float* zp = z + (size_t)bc * NZ;
    for (int i = threadIdx.x; i < NX; i += 192) xs[i] = xp[i];
    for (int i = threadIdx.x; i < NZ; i += 192) zs[i] = zp[i];

    float a = w3[0], b = w3[1], c = w3[2];
    float mx = fmaxf(a, fmaxf(b, c));
    float e0 = expf(a - mx), e1 = expf(b - mx), e2 = expf(c - mx);
    float wt = (IDX == 0 ? e0 : (IDX == 1 ? e1 : e2)) / (e0 + e1 + e2);
    __syncthreads();

    int t = threadIdx.x;
    if (t >= 153) return;
    int oh = t / 9, owp = t % 9, ow0 = owp * 2;
    float s0 = 0.0f, s1 = 0.0f;
#pragma unroll 1
    for (int kh = 0; kh < HZ_; kh++) {
        const float* xr = &xs[(oh + kh) * WX_ + ow0];
        const float* zr = &zs[kh * WZ_];
#pragma unroll
        for (int kw = 0; kw < WZ_; kw++) {
            float zv = zr[kw];
            s0 = fmaf(xr[kw], zv, s0);
            s1 = fmaf(xr[kw + 1], zv, s1);
        }
    }
    size_t o = (size_t)bc * 289 + oh * 17 + ow0;
    if (IDX == 0) {
        out[o] = wt * s0;
        if (owp < 8) out[o + 1] = wt * s1;
    } else {
        out[o] += wt * s0;
        if (owp < 8) out[o + 1] += wt * s1;
    }
}

// ---------------- bbox pred ----------------
__global__ __launch_bounds__(320) void bp_pred(
    const float* __restrict__ xr, const float* __restrict__ w,
    const float* __restrict__ wb, const float* __restrict__ adj,
    const float* __restrict__ bia, float* __restrict__ outx)
{
    int b = blockIdx.x;
    int p = threadIdx.x;
    if (p >= 289) return;
    int oh = p / 17, ow = p % 17;
    float acc[4] = {0.f, 0.f, 0.f, 0.f};
    const float* xb = xr + (size_t)b * 256 * 289;
#pragma unroll 1
    for (int cin = 0; cin < 256; cin++) {
        const float* ip = xb + (size_t)cin * 289;
#pragma unroll
        for (int kh = 0; kh < 3; kh++) {
            int ih = oh - 1 + kh;
            bool okh = (unsigned)ih < 17u;
            int ihc = okh ? ih : 0;
#pragma unroll
            for (int kw = 0; kw < 3; kw++) {
                int iw = ow - 1 + kw;
                bool ok = okh && ((unsigned)iw < 17u);
                int iwc = ok ? iw : 0;
                float v = ip[ihc * 17 + iwc];
                v = ok ? v : 0.0f;
#pragma unroll
                for (int co = 0; co < 4; co++)
                    acc[co] = fmaf(v, w[(size_t)(co * 256 + cin) * 9 + kh * 3 + kw], acc[co]);
            }
        }
    }
    float ad = adj[0];
#pragma unroll
    for (int co = 0; co < 4; co++) {
        float t2 = fmaf(ad, acc[co] + wb[co], bia[co]);
        outx[((size_t)b * 4 + co) * 289 + p] = expf(fminf(t2, 4.7f));
    }
}

// ---------------- cls pred ----------------
__global__ __launch_bounds__(320) void cp_pred(
    const float* __restrict__ cfeat, const float* __restrict__ w,
    const float* __restrict__ wb, float* __restrict__ outc)
{
    int b = blockIdx.x;
    int p = threadIdx.x;
    if (p >= 289) return;
    int oh = p / 17, ow = p % 17;
    float acc = 0.f;
#pragma unroll 1
    for (int cin = 0; cin < 256; cin++) {
        const float* ip = cfeat + ((size_t)b * 256 + cin) * 289;
#pragma unroll
        for (int kh = 0; kh < 3; kh++) {
            int ih = oh - 1 + kh;
            bool okh = (unsigned)ih < 17u;
            int ihc = okh ? ih : 0;
#pragma unroll
            for (int kw = 0; kw < 3; kw++) {
                int iw = ow - 1 + kw;
                bool ok = okh && ((unsigned)iw < 17u);
                int iwc = ok ? iw : 0;
                float v = ip[ihc * 17 + iwc];
                v = ok ? v : 0.0f;
                acc = fmaf(v, w[(size_t)cin * 9 + kh * 3 + kw], acc);
            }
        }
    }
    outc[(size_t)b * 289 + p] = 0.1f * (acc + wb[0]);
}

// ---------------- host launch ----------------
extern "C" void kernel_launch(void* const* d_in, const int* in_sizes, int n_in,
                              void* d_out, int out_size, void* d_ws, size_t ws_size,
                              hipStream_t stream)
{
    (void)in_sizes; (void)n_in; (void)out_size; (void)ws_size;
    const float* search = (const float*)d_in[0];
    const float* kern   = (const float*)d_in[1];
    const float* cls_mw = (const float*)d_in[2];
    const float* reg_mw = (const float*)d_in[7];
    const float* cls_dww = (const float*)d_in[12];
    const float* reg_dww = (const float*)d_in[13];
    const float* btw = (const float*)d_in[14];
    const float* ctw = (const float*)d_in[19];
    const float* bpw = (const float*)d_in[24];
    const float* bpb = (const float*)d_in[25];
    const float* cpw = (const float*)d_in[26];
    const float* cpb = (const float*)d_in[27];
    const float* adj = (const float*)d_in[28];
    const float* bia = (const float*)d_in[29];

    float* ws  = (float*)d_ws;
    float* out = (float*)d_out;

    ushortT* wt_hi = (ushortT*)(ws + WT_HI);
    ushortT* wt_lo = (ushortT*)(ws + WT_LO);
    ushortT* s_hi  = (ushortT*)(ws + INT_SH);
    ushortT* s_lo  = (ushortT*)(ws + INT_SL);
    ushortT* z_hi  = (ushortT*)(ws + INT_ZH);
    ushortT* z_lo  = (ushortT*)(ws + INT_ZL);

    fold_bn_k<<<1, 256, 0, stream>>>(
        (const float*)d_in[3], (const float*)d_in[4], (const float*)d_in[5], (const float*)d_in[6],
        (const float*)d_in[8], (const float*)d_in[9], (const float*)d_in[10], (const float*)d_in[11],
        (const float*)d_in[15], (const float*)d_in[16], (const float*)d_in[17], (const float*)d_in[18],
        (const float*)d_in[20], (const float*)d_in[21], (const float*)d_in[22], (const float*)d_in[23],
        ws);

    // input transforms (shared across both branches)
    nchw2nhwc_split<<<dim3(31, 8, 64), dim3(32, 8), 0, stream>>>(search, s_hi, s_lo, 961);
    nchw2nhwc_split<<<dim3(8, 8, 64), dim3(32, 8), 0, stream>>>(kern, z_hi, z_lo, 225);

    const size_t WC = (size_t)2304 * 256; // per-conv wt plane stride (ushorts)

    auto branch = [&](const float* mw, const float* sbb, const float* dww, float* dwout) {
        wt_split<<<1536, 256, 0, stream>>>(mw, wt_hi, wt_lo);
        // pair 0: dil (1,1): z 13x13, x 29x29
        mfma_conv<1, 1, 13, 13, 15, 15><<<dim3(2, 2, 64), 256, 0, stream>>>(
            z_hi, z_lo, wt_hi + 0 * WC, wt_lo + 0 * WC, sbb + 0 * 512, ws + WS_ZB);
        mfma_conv<1, 1, 29, 29, 31, 31><<<dim3(7, 2, 64), 256, 0, stream>>>(
            s_hi, s_lo, wt_hi + 1 * WC, wt_lo + 1 * WC, sbb + 1 * 512, ws + WS_XB);
        xcorr_one<13, 13, 29, 0><<<16384, 192, 0, stream>>>(ws + WS_ZB, ws + WS_XB, dww, dwout);
        // pair 1: dil (2,1): z 11x13, x 27x29
        mfma_conv<2, 1, 11, 13, 15, 15><<<dim3(2, 2, 64), 256, 0, stream>>>(
            z_hi, z_lo, wt_hi + 2 * WC, wt_lo + 2 * WC, sbb + 2 * 512, ws + WS_ZB);
        mfma_conv<2, 1, 27, 29, 31, 31><<<dim3(7, 2, 64), 256, 0, stream>>>(
            s_hi, s_lo, wt_hi + 3 * WC, wt_lo + 3 * WC, sbb + 3 * 512, ws + WS_XB);
        xcorr_one<11, 13, 29, 1><<<16384, 192, 0, stream>>>(ws + WS_ZB, ws + WS_XB, dww, dwout);
        // pair 2: dil (1,2): z 13x11, x 29x27
        mfma_conv<1, 2, 13, 11, 15, 15><<<dim3(2, 2, 64), 256, 0, stream>>>(
            z_hi, z_lo, wt_hi + 4 * WC, wt_lo + 4 * WC, sbb + 4 * 512, ws + WS_ZB);
        mfma_conv<1, 2, 29, 27, 31, 31><<<dim3(7, 2, 64), 256, 0, stream>>>(
            s_hi, s_lo, wt_hi + 5 * WC, wt_lo + 5 * WC, sbb + 5 * 512, ws + WS_XB);
        xcorr_one<13, 11, 27, 2><<<16384, 192, 0, stream>>>(ws + WS_ZB, ws + WS_XB, dww, dwout);
    };

    // cls branch -> cls_dw directly in d_out; reg branch -> ws
    branch(cls_mw, ws + SB_CLS, cls_dww, out + O_CDW);
    branch(reg_mw, ws + SB_REG, reg_dww, ws + WS_RDW);

    // bbox tower: CBR(reg_dw) -> x_reg (d_out), then bp conv + exp -> x (d_out)
    cbr_conv<1, 1, 1, 1><<<dim3(2, 16, 64), 256, 0, stream>>>(
        ws + WS_RDW, btw, ws + SB_BT, out + O_XREG, 17, 17, 17, 17);
    bp_pred<<<64, 320, 0, stream>>>(out + O_XREG, bpw, bpb, adj, bia, out + O_X);

    // cls tower: CBR(cls_dw) -> c (ws), then cp conv -> cls (d_out)
    cbr_conv<1, 1, 1, 1><<<dim3(2, 16, 64), 256, 0, stream>>>(
        out + O_CDW, ctw, ws + SB_CT, ws + WS_CB, 17, 17, 17, 17);
    cp_pred<<<64, 320, 0, stream>>>(ws + WS_CB, cpw, cpb, out + O_CLS);
}

// Round 4
// 3212.165 us; speedup vs baseline: 3.0405x; 1.4571x over previous
//
#include <hip/hip_runtime.h>
#include <math.h>

typedef unsigned short ushortT;
typedef unsigned int uintT;

using bf8   = __attribute__((ext_vector_type(8))) short;
using f32x4 = __attribute__((ext_vector_type(4))) float;

// ---------------- problem constants ----------------
// B=64, C=256, z=15x15, x=31x31, outputs on 17x17 grid.

// ws float offsets
#define SB_CLS 0
#define SB_REG 3072
#define SB_BT  6144
#define SB_CT  6656
#define WT_HI   ((size_t)8192)
#define WT_LO   (WT_HI + (size_t)1769472)
#define INT_SH  (WT_LO + (size_t)1769472)
#define INT_SL  (INT_SH + (size_t)7872512)
#define INT_ZH  (INT_SL + (size_t)7872512)
#define INT_ZL  (INT_ZH + (size_t)1843200)
#define WS_ZB   (INT_ZL + (size_t)1843200)              // f32 64*256*169
#define WS_XB   (WS_ZB + (size_t)2768896)               // f32 64*256*841
#define WS_RDW  (WS_XB + (size_t)13778944)              // f32 64*256*289
#define WS_CB   WS_XB                                   // cls tower feature reuses XB
// total ws floats = WS_RDW + 4734976 = 44,261,376 (~177 MB)
// tower-phase reuse (search NHWC + wt regions are dead by then):
//   padded NHWC hi -> INT_SH, lo -> INT_SL  (needs 2,957,312 floats each; have 7.87M)
//   tower weights  -> WT_HI/WT_LO slots 0 (bt) and 1 (ct)

// d_out float offsets (x, cls, cls_dw, x_reg concatenated)
#define O_X    ((size_t)0)
#define O_CLS  ((size_t)73984)
#define O_CDW  ((size_t)92480)
#define O_XREG ((size_t)4827456)

// ---------------- helpers ----------------
__device__ __forceinline__ ushortT f2bf(float v) {
    uintT u = __float_as_uint(v);
    uintT r = ((u >> 16) & 1u) + 0x7fffu;   // round-to-nearest-even
    return (ushortT)((u + r) >> 16);
}
__device__ __forceinline__ float bf2f(ushortT h) {
    return __uint_as_float(((uintT)h) << 16);
}
__device__ __forceinline__ void gl16(const ushortT* g, ushortT* l) {
    __builtin_amdgcn_global_load_lds(
        (const __attribute__((address_space(1))) void*)g,
        (__attribute__((address_space(3))) void*)l, 16, 0, 0);
}

// ---------------- BN folding ----------------
__global__ void fold_bn_k(const float* __restrict__ cg, const float* __restrict__ cb,
                          const float* __restrict__ cm, const float* __restrict__ cv,
                          const float* __restrict__ rg, const float* __restrict__ rb,
                          const float* __restrict__ rm, const float* __restrict__ rv,
                          const float* __restrict__ btg, const float* __restrict__ btb,
                          const float* __restrict__ btm, const float* __restrict__ btv,
                          const float* __restrict__ ctg, const float* __restrict__ ctb,
                          const float* __restrict__ ctm, const float* __restrict__ ctv,
                          float* __restrict__ sb)
{
    int c = threadIdx.x; // 256
    for (int i = 0; i < 6; i++) {
        float s = cg[i*256 + c] * rsqrtf(cv[i*256 + c] + 1e-5f);
        sb[SB_CLS + i*512 + c]       = s;
        sb[SB_CLS + i*512 + 256 + c] = cb[i*256 + c] - cm[i*256 + c] * s;
        float s2 = rg[i*256 + c] * rsqrtf(rv[i*256 + c] + 1e-5f);
        sb[SB_REG + i*512 + c]       = s2;
        sb[SB_REG + i*512 + 256 + c] = rb[i*256 + c] - rm[i*256 + c] * s2;
    }
    float s = btg[c] * rsqrtf(btv[c] + 1e-5f);
    sb[SB_BT + c] = s; sb[SB_BT + 256 + c] = btb[c] - btm[c] * s;
    s = ctg[c] * rsqrtf(ctv[c] + 1e-5f);
    sb[SB_CT + c] = s; sb[SB_CT + 256 + c] = ctb[c] - ctm[c] * s;
}

// ---------------- NCHW f32 -> NHWC bf16 hi/lo planes ----------------
// grid (ceil(HW/32), 8, B), block (32,8)
__global__ __launch_bounds__(256) void nchw2nhwc_split(
    const float* __restrict__ in, ushortT* __restrict__ hi, ushortT* __restrict__ lo, int HW)
{
    __shared__ float t[32][33];
    const int b = blockIdx.z, ci0 = blockIdx.y * 32, p0 = blockIdx.x * 32;
    const int tx = threadIdx.x, ty = threadIdx.y;
    for (int i = 0; i < 32; i += 8) {
        int ci = ci0 + ty + i, p = p0 + tx;
        t[ty + i][tx] = (p < HW) ? in[((size_t)(b * 256 + ci)) * HW + p] : 0.0f;
    }
    __syncthreads();
    for (int i = 0; i < 32; i += 8) {
        int p = p0 + ty + i;
        if (p < HW) {
            float v = t[tx][ty + i];
            ushortT h = f2bf(v);
            ushortT l = f2bf(v - bf2f(h));
            size_t o = ((size_t)b * HW + p) * 256 + ci0 + tx;
            hi[o] = h; lo[o] = l;
        }
    }
}

// ---------------- NCHW f32 17x17 -> padded 19x19 NHWC bf16 hi/lo (interior only) ----------------
// grid (10, 8, 64), block (32,8). Border must be pre-zeroed.
__global__ __launch_bounds__(256) void nchw2nhwc_pad_split(
    const float* __restrict__ in, ushortT* __restrict__ hi, ushortT* __restrict__ lo)
{
    __shared__ float t[32][33];
    const int b = blockIdx.z, ci0 = blockIdx.y * 32, p0 = blockIdx.x * 32;
    const int tx = threadIdx.x, ty = threadIdx.y;
    for (int i = 0; i < 32; i += 8) {
        int ci = ci0 + ty + i, p = p0 + tx;
        t[ty + i][tx] = (p < 289) ? in[((size_t)(b * 256 + ci)) * 289 + p] : 0.0f;
    }
    __syncthreads();
    for (int i = 0; i < 32; i += 8) {
        int p = p0 + ty + i;
        if (p < 289) {
            float v = t[tx][ty + i];
            ushortT h = f2bf(v);
            ushortT l = f2bf(v - bf2f(h));
            int pp = (p / 17 + 1) * 19 + (p % 17 + 1);
            size_t o = ((size_t)b * 361 + pp) * 256 + ci0 + tx;
            hi[o] = h; lo[o] = l;
        }
    }
}

// ---------------- zero padded NHWC buffers ----------------
__global__ __launch_bounds__(256) void zero_pad_k(ushortT* __restrict__ hi, ushortT* __restrict__ lo)
{
    const size_t n16 = (size_t)64 * 361 * 256 / 8;  // uint4 count per plane
    uint4 z; z.x = z.y = z.z = z.w = 0u;
    uint4* h4 = (uint4*)hi; uint4* l4 = (uint4*)lo;
    for (size_t i = blockIdx.x * 256 + threadIdx.x; i < n16; i += (size_t)gridDim.x * 256) {
        h4[i] = z; l4[i] = z;
    }
}

// ---------------- weight transform: [co][ci][9] -> [co][kidx*256+ci] hi/lo ----------------
// grid nconv*256 blocks (conv, co), block 256
__global__ __launch_bounds__(256) void wt_split(
    const float* __restrict__ w, ushortT* __restrict__ whi, ushortT* __restrict__ wlo)
{
    const int co = blockIdx.x & 255, conv = blockIdx.x >> 8;
    const float* src = w + ((size_t)conv * 256 + co) * 2304;
    __shared__ float lw[2304];
    const int t = threadIdx.x;
#pragma unroll
    for (int i = 0; i < 9; i++) lw[i * 256 + t] = src[i * 256 + t];
    __syncthreads();
    size_t ob = ((size_t)conv * 256 + co) * 2304;
#pragma unroll
    for (int i = 0; i < 9; i++) {
        float v = lw[t * 9 + i];
        ushortT h = f2bf(v);
        whi[ob + i * 256 + t] = h;
        wlo[ob + i * 256 + t] = f2bf(v - bf2f(h));
    }
}

// ---------------- MFMA implicit-GEMM conv (VALID, dilated) + BN + relu ----------------
// A: in_t NHWC bf16 hi/lo [B][HI][WI][256]; B: wt [co][kidx*256+ci] hi/lo
// out f32 NCHW [B][256][Ho*Wo]. grid (ceil(npos/128), 2, B), block 256 (4 waves).
// Split-bf16: acc += Ahi*Bhi + Ahi*Blo + Alo*Bhi  (near-f32 accuracy).
// 64-wide K chunks: one barrier pair per 64-K (vs 32-K before).
template <int DH, int DW, int Ho, int Wo, int HI, int WI>
__global__ __launch_bounds__(256, 2) void mfma_conv(
    const ushortT* __restrict__ ahi, const ushortT* __restrict__ alo,
    const ushortT* __restrict__ whi, const ushortT* __restrict__ wlo,
    const float* __restrict__ sb, float* __restrict__ out)
{
    constexpr int NPOS = Ho * Wo;
    __shared__ __align__(16) ushortT lds[4][8192];   // planes A_hi,A_lo,B_hi,B_lo: [128 rows][64 k]

    const int t = threadIdx.x, lane = t & 63, wave = t >> 6;
    const int b = blockIdx.z, cog = blockIdx.y;
    const int m0 = blockIdx.x * 128;
    const int wrow = wave >> 1, wcol = wave & 1;

    // staging: for q in 0..3, row = q*32 + wave*8 + (lane>>3), 16B chunk = lane&7
    const int lrow = lane >> 3, e8 = (lane & 7) * 8;
    int aoh[4], aow[4];
    size_t wrb[4];
#pragma unroll
    for (int q = 0; q < 4; q++) {
        int r = q * 32 + wave * 8 + lrow;
        int p = m0 + r; if (p > NPOS - 1) p = NPOS - 1;
        aoh[q] = p / Wo; aow[q] = p - aoh[q] * Wo;
        wrb[q] = (size_t)(cog * 128 + r) * 2304 + e8;
    }

    f32x4 acc[4][4];
#pragma unroll
    for (int i = 0; i < 4; i++)
#pragma unroll
        for (int j = 0; j < 4; j++) acc[i][j] = (f32x4){0.f, 0.f, 0.f, 0.f};

    const int arow = lane & 15, koff = (lane >> 4) * 8;

#pragma unroll 1
    for (int kidx = 0; kidx < 9; ++kidx) {
        const int kh = kidx / 3, kw = kidx - kh * 3;
        size_t ab[4];
#pragma unroll
        for (int q = 0; q < 4; q++)
            ab[q] = ((size_t)((b * HI) + aoh[q] + DH * kh) * WI + aow[q] + DW * kw) * 256 + e8;
        const size_t wk = (size_t)kidx * 256;
#pragma unroll 1
        for (int s = 0; s < 4; ++s) {
            const int cs = s * 64;
#pragma unroll
            for (int q = 0; q < 4; q++) {
                const int dst = (q * 32 + wave * 8) * 64;   // wave-uniform; HW adds lane*16B
                gl16(ahi + ab[q] + cs, &lds[0][dst]);
                gl16(alo + ab[q] + cs, &lds[1][dst]);
                gl16(whi + wrb[q] + wk + cs, &lds[2][dst]);
                gl16(wlo + wrb[q] + wk + cs, &lds[3][dst]);
            }
            __syncthreads();
#pragma unroll
            for (int kk = 0; kk < 2; ++kk) {
                const int ko = kk * 32 + koff;
                bf8 ah[4], al[4], bh[4], bl[4];
#pragma unroll
                for (int mt = 0; mt < 4; ++mt) {
                    int r = wrow * 64 + mt * 16 + arow;
                    ah[mt] = *(const bf8*)&lds[0][r * 64 + ko];
                    al[mt] = *(const bf8*)&lds[1][r * 64 + ko];
                }
#pragma unroll
                for (int nt = 0; nt < 4; ++nt) {
                    int r = wcol * 64 + nt * 16 + arow;
                    bh[nt] = *(const bf8*)&lds[2][r * 64 + ko];
                    bl[nt] = *(const bf8*)&lds[3][r * 64 + ko];
                }
#pragma unroll
                for (int mt = 0; mt < 4; ++mt)
#pragma unroll
                    for (int nt = 0; nt < 4; ++nt) {
                        acc[mt][nt] = __builtin_amdgcn_mfma_f32_16x16x32_bf16(ah[mt], bh[nt], acc[mt][nt], 0, 0, 0);
                        acc[mt][nt] = __builtin_amdgcn_mfma_f32_16x16x32_bf16(ah[mt], bl[nt], acc[mt][nt], 0, 0, 0);
                        acc[mt][nt] = __builtin_amdgcn_mfma_f32_16x16x32_bf16(al[mt], bh[nt], acc[mt][nt], 0, 0, 0);
                    }
            }
            __syncthreads();
        }
    }

    // epilogue: folded BN + relu, f32 NCHW store
#pragma unroll
    for (int nt = 0; nt < 4; ++nt) {
        const int co = cog * 128 + wcol * 64 + nt * 16 + arow;
        const float scl = sb[co], bia = sb[256 + co];
        const size_t ob = ((size_t)b * 256 + co) * NPOS;
#pragma unroll
        for (int mt = 0; mt < 4; ++mt)
#pragma unroll
            for (int r = 0; r < 4; ++r) {
                int p = m0 + wrow * 64 + mt * 16 + (lane >> 4) * 4 + r;
                if (p < NPOS) {
                    float v = fmaf(acc[mt][nt][r], scl, bia);
                    out[ob + p] = v > 0.f ? v : 0.f;
                }
            }
    }
}

// ---------------- depthwise xcorr (one of 3), softmax-weighted accumulate ----------------
template <int HZ_, int WZ_, int WX_, int IDX>
__global__ __launch_bounds__(192) void xcorr_one(
    const float* __restrict__ z, const float* __restrict__ x,
    const float* __restrict__ w3, float* __restrict__ out)
{
    constexpr int HX_ = 16 + HZ_;
    constexpr int NX = HX_ * WX_;
    constexpr int NZ = HZ_ * WZ_;
    __shared__ float xs[NX + 4];
    __shared__ float zs[NZ];
    const int bc = blockIdx.x;
    const float* xp = x + (size_t)bc * NX;
    const float* zp = z + (size_t)bc * NZ;
    for (int i = threadIdx.x; i < NX; i += 192) xs[i] = xp[i];
    for (int i = threadIdx.x; i < NZ; i += 192) zs[i] = zp[i];

    float a = w3[0], b = w3[1], c = w3[2];
    float mx = fmaxf(a, fmaxf(b, c));
    float e0 = expf(a - mx), e1 = expf(b - mx), e2 = expf(c - mx);
    float wt = (IDX == 0 ? e0 : (IDX == 1 ? e1 : e2)) / (e0 + e1 + e2);
    __syncthreads();

    int t = threadIdx.x;
    if (t >= 153) return;
    int oh = t / 9, owp = t % 9, ow0 = owp * 2;
    float s0 = 0.0f, s1 = 0.0f;
#pragma unroll 1
    for (int kh = 0; kh < HZ_; kh++) {
        const float* xr = &xs[(oh + kh) * WX_ + ow0];
        const float* zr = &zs[kh * WZ_];
#pragma unroll
        for (int kw = 0; kw < WZ_; kw++) {
            float zv = zr[kw];
            s0 = fmaf(xr[kw], zv, s0);
            s1 = fmaf(xr[kw + 1], zv, s1);
        }
    }
    size_t o = (size_t)bc * 289 + oh * 17 + ow0;
    if (IDX == 0) {
        out[o] = wt * s0;
        if (owp < 8) out[o + 1] = wt * s1;
    } else {
        out[o] += wt * s0;
        if (owp < 8) out[o + 1] += wt * s1;
    }
}

// ---------------- bbox pred ----------------
__global__ __launch_bounds__(320) void bp_pred(
    const float* __restrict__ xr, const float* __restrict__ w,
    const float* __restrict__ wb, const float* __restrict__ adj,
    const float* __restrict__ bia, float* __restrict__ outx)
{
    int b = blockIdx.x;
    int p = threadIdx.x;
    if (p >= 289) return;
    int oh = p / 17, ow = p % 17;
    float acc[4] = {0.f, 0.f, 0.f, 0.f};
    const float* xb = xr + (size_t)b * 256 * 289;
#pragma unroll 1
    for (int cin = 0; cin < 256; cin++) {
        const float* ip = xb + (size_t)cin * 289;
#pragma unroll
        for (int kh = 0; kh < 3; kh++) {
            int ih = oh - 1 + kh;
            bool okh = (unsigned)ih < 17u;
            int ihc = okh ? ih : 0;
#pragma unroll
            for (int kw = 0; kw < 3; kw++) {
                int iw = ow - 1 + kw;
                bool ok = okh && ((unsigned)iw < 17u);
                int iwc = ok ? iw : 0;
                float v = ip[ihc * 17 + iwc];
                v = ok ? v : 0.0f;
#pragma unroll
                for (int co = 0; co < 4; co++)
                    acc[co] = fmaf(v, w[(size_t)(co * 256 + cin) * 9 + kh * 3 + kw], acc[co]);
            }
        }
    }
    float ad = adj[0];
#pragma unroll
    for (int co = 0; co < 4; co++) {
        float t2 = fmaf(ad, acc[co] + wb[co], bia[co]);
        outx[((size_t)b * 4 + co) * 289 + p] = expf(fminf(t2, 4.7f));
    }
}

// ---------------- cls pred ----------------
__global__ __launch_bounds__(320) void cp_pred(
    const float* __restrict__ cfeat, const float* __restrict__ w,
    const float* __restrict__ wb, float* __restrict__ outc)
{
    int b = blockIdx.x;
    int p = threadIdx.x;
    if (p >= 289) return;
    int oh = p / 17, ow = p % 17;
    float acc = 0.f;
#pragma unroll 1
    for (int cin = 0; cin < 256; cin++) {
        const float* ip = cfeat + ((size_t)b * 256 + cin) * 289;
#pragma unroll
        for (int kh = 0; kh < 3; kh++) {
            int ih = oh - 1 + kh;
            bool okh = (unsigned)ih < 17u;
            int ihc = okh ? ih : 0;
#pragma unroll
            for (int kw = 0; kw < 3; kw++) {
                int iw = ow - 1 + kw;
                bool ok = okh && ((unsigned)iw < 17u);
                int iwc = ok ? iw : 0;
                float v = ip[ihc * 17 + iwc];
                v = ok ? v : 0.0f;
                acc = fmaf(v, w[(size_t)cin * 9 + kh * 3 + kw], acc);
            }
        }
    }
    outc[(size_t)b * 289 + p] = 0.1f * (acc + wb[0]);
}

// ---------------- host launch ----------------
extern "C" void kernel_launch(void* const* d_in, const int* in_sizes, int n_in,
                              void* d_out, int out_size, void* d_ws, size_t ws_size,
                              hipStream_t stream)
{
    (void)in_sizes; (void)n_in; (void)out_size; (void)ws_size;
    const float* search = (const float*)d_in[0];
    const float* kern   = (const float*)d_in[1];
    const float* cls_mw = (const float*)d_in[2];
    const float* reg_mw = (const float*)d_in[7];
    const float* cls_dww = (const float*)d_in[12];
    const float* reg_dww = (const float*)d_in[13];
    const float* btw = (const float*)d_in[14];
    const float* ctw = (const float*)d_in[19];
    const float* bpw = (const float*)d_in[24];
    const float* bpb = (const float*)d_in[25];
    const float* cpw = (const float*)d_in[26];
    const float* cpb = (const float*)d_in[27];
    const float* adj = (const float*)d_in[28];
    const float* bia = (const float*)d_in[29];

    float* ws  = (float*)d_ws;
    float* out = (float*)d_out;

    ushortT* wt_hi = (ushortT*)(ws + WT_HI);
    ushortT* wt_lo = (ushortT*)(ws + WT_LO);
    ushortT* s_hi  = (ushortT*)(ws + INT_SH);
    ushortT* s_lo  = (ushortT*)(ws + INT_SL);
    ushortT* z_hi  = (ushortT*)(ws + INT_ZH);
    ushortT* z_lo  = (ushortT*)(ws + INT_ZL);
    // tower-phase aliases (search NHWC + wt regions dead by then)
    ushortT* pad_hi = s_hi;
    ushortT* pad_lo = s_lo;

    fold_bn_k<<<1, 256, 0, stream>>>(
        (const float*)d_in[3], (const float*)d_in[4], (const float*)d_in[5], (const float*)d_in[6],
        (const float*)d_in[8], (const float*)d_in[9], (const float*)d_in[10], (const float*)d_in[11],
        (const float*)d_in[15], (const float*)d_in[16], (const float*)d_in[17], (const float*)d_in[18],
        (const float*)d_in[20], (const float*)d_in[21], (const float*)d_in[22], (const float*)d_in[23],
        ws);

    // input transforms (shared across both branches)
    nchw2nhwc_split<<<dim3(31, 8, 64), dim3(32, 8), 0, stream>>>(search, s_hi, s_lo, 961);
    nchw2nhwc_split<<<dim3(8, 8, 64), dim3(32, 8), 0, stream>>>(kern, z_hi, z_lo, 225);

    const size_t WC = (size_t)2304 * 256; // per-conv wt plane stride (ushorts)

    auto branch = [&](const float* mw, const float* sbb, const float* dww, float* dwout) {
        wt_split<<<1536, 256, 0, stream>>>(mw, wt_hi, wt_lo);
        // pair 0: dil (1,1): z 13x13, x 29x29
        mfma_conv<1, 1, 13, 13, 15, 15><<<dim3(2, 2, 64), 256, 0, stream>>>(
            z_hi, z_lo, wt_hi + 0 * WC, wt_lo + 0 * WC, sbb + 0 * 512, ws + WS_ZB);
        mfma_conv<1, 1, 29, 29, 31, 31><<<dim3(7, 2, 64), 256, 0, stream>>>(
            s_hi, s_lo, wt_hi + 1 * WC, wt_lo + 1 * WC, sbb + 1 * 512, ws + WS_XB);
        xcorr_one<13, 13, 29, 0><<<16384, 192, 0, stream>>>(ws + WS_ZB, ws + WS_XB, dww, dwout);
        // pair 1: dil (2,1): z 11x13, x 27x29
        mfma_conv<2, 1, 11, 13, 15, 15><<<dim3(2, 2, 64), 256, 0, stream>>>(
            z_hi, z_lo, wt_hi + 2 * WC, wt_lo + 2 * WC, sbb + 2 * 512, ws + WS_ZB);
        mfma_conv<2, 1, 27, 29, 31, 31><<<dim3(7, 2, 64), 256, 0, stream>>>(
            s_hi, s_lo, wt_hi + 3 * WC, wt_lo + 3 * WC, sbb + 3 * 512, ws + WS_XB);
        xcorr_one<11, 13, 29, 1><<<16384, 192, 0, stream>>>(ws + WS_ZB, ws + WS_XB, dww, dwout);
        // pair 2: dil (1,2): z 13x11, x 29x27
        mfma_conv<1, 2, 13, 11, 15, 15><<<dim3(2, 2, 64), 256, 0, stream>>>(
            z_hi, z_lo, wt_hi + 4 * WC, wt_lo + 4 * WC, sbb + 4 * 512, ws + WS_ZB);
        mfma_conv<1, 2, 29, 27, 31, 31><<<dim3(7, 2, 64), 256, 0, stream>>>(
            s_hi, s_lo, wt_hi + 5 * WC, wt_lo + 5 * WC, sbb + 5 * 512, ws + WS_XB);
        xcorr_one<13, 11, 27, 2><<<16384, 192, 0, stream>>>(ws + WS_ZB, ws + WS_XB, dww, dwout);
    };

    // cls branch -> cls_dw directly in d_out; reg branch -> ws
    branch(cls_mw, ws + SB_CLS, cls_dww, out + O_CDW);
    branch(reg_mw, ws + SB_REG, reg_dww, ws + WS_RDW);

    // ---- towers (MFMA path): search NHWC + wt regions now dead, reuse them ----
    wt_split<<<256, 256, 0, stream>>>(btw, wt_hi, wt_lo);                 // slot 0 = bt
    wt_split<<<256, 256, 0, stream>>>(ctw, wt_hi + WC, wt_lo + WC);       // slot 1 = ct
    zero_pad_k<<<1024, 256, 0, stream>>>(pad_hi, pad_lo);

    // bbox tower: pad(reg_dw) -> mfma conv -> x_reg (d_out), then bp conv + exp -> x (d_out)
    nchw2nhwc_pad_split<<<dim3(10, 8, 64), dim3(32, 8), 0, stream>>>(ws + WS_RDW, pad_hi, pad_lo);
    mfma_conv<1, 1, 17, 17, 19, 19><<<dim3(3, 2, 64), 256, 0, stream>>>(
        pad_hi, pad_lo, wt_hi, wt_lo, ws + SB_BT, out + O_XREG);
    bp_pred<<<64, 320, 0, stream>>>(out + O_XREG, bpw, bpb, adj, bia, out + O_X);

    // cls tower: pad(cls_dw) -> mfma conv -> c (ws), then cp conv -> cls (d_out)
    // (border zeros persist from zero_pad_k; interior fully rewritten)
    nchw2nhwc_pad_split<<<dim3(10, 8, 64), dim3(32, 8), 0, stream>>>(out + O_CDW, pad_hi, pad_lo);
    mfma_conv<1, 1, 17, 17, 19, 19><<<dim3(3, 2, 64), 256, 0, stream>>>(
        pad_hi, pad_lo, wt_hi + WC, wt_lo + WC, ws + SB_CT, ws + WS_CB);
    cp_pred<<<64, 320, 0, stream>>>(ws + WS_CB, cpw, cpb, out + O_CLS);
}

// Round 5
// 2811.934 us; speedup vs baseline: 3.4732x; 1.1423x over previous
//
#include <hip/hip_runtime.h>
#include <math.h>

typedef unsigned short ushortT;
typedef unsigned int uintT;

using bf8   = __attribute__((ext_vector_type(8))) short;
using f32x4 = __attribute__((ext_vector_type(4))) float;

// ---------------- problem constants ----------------
// B=64, C=256, z=15x15, x=31x31, outputs on 17x17 grid.

// ws float offsets
#define SB_CLS 0
#define SB_REG 3072
#define SB_BT  6144
#define SB_CT  6656
#define WT_HI   ((size_t)8192)
#define WT_LO   (WT_HI + (size_t)1769472)
#define INT_SH  (WT_LO + (size_t)1769472)
#define INT_SL  (INT_SH + (size_t)7872512)
#define INT_ZH  (INT_SL + (size_t)7872512)
#define INT_ZL  (INT_ZH + (size_t)1843200)
#define WS_ZB   (INT_ZL + (size_t)1843200)              // f32 64*256*169
#define WS_XB   (WS_ZB + (size_t)2768896)               // f32 64*256*841
#define WS_RDW  (WS_XB + (size_t)13778944)              // f32 64*256*289
#define WS_CB   WS_XB                                   // cls tower feature reuses XB
// total ws floats = WS_RDW + 4734976 = 44,261,376 (~177 MB)
// tower-phase reuse (search NHWC + wt regions are dead by then):
//   padded NHWC hi -> INT_SH, lo -> INT_SL; tower weights -> WT slots 0 (bt), 1 (ct)

// d_out float offsets (x, cls, cls_dw, x_reg concatenated)
#define O_X    ((size_t)0)
#define O_CLS  ((size_t)73984)
#define O_CDW  ((size_t)92480)
#define O_XREG ((size_t)4827456)

// ---------------- helpers ----------------
__device__ __forceinline__ ushortT f2bf(float v) {
    uintT u = __float_as_uint(v);
    uintT r = ((u >> 16) & 1u) + 0x7fffu;   // round-to-nearest-even
    return (ushortT)((u + r) >> 16);
}
__device__ __forceinline__ float bf2f(ushortT h) {
    return __uint_as_float(((uintT)h) << 16);
}
__device__ __forceinline__ void gl16(const ushortT* g, ushortT* l) {
    __builtin_amdgcn_global_load_lds(
        (const __attribute__((address_space(1))) void*)g,
        (__attribute__((address_space(3))) void*)l, 16, 0, 0);
}

// ---------------- BN folding ----------------
__global__ void fold_bn_k(const float* __restrict__ cg, const float* __restrict__ cb,
                          const float* __restrict__ cm, const float* __restrict__ cv,
                          const float* __restrict__ rg, const float* __restrict__ rb,
                          const float* __restrict__ rm, const float* __restrict__ rv,
                          const float* __restrict__ btg, const float* __restrict__ btb,
                          const float* __restrict__ btm, const float* __restrict__ btv,
                          const float* __restrict__ ctg, const float* __restrict__ ctb,
                          const float* __restrict__ ctm, const float* __restrict__ ctv,
                          float* __restrict__ sb)
{
    int c = threadIdx.x; // 256
    for (int i = 0; i < 6; i++) {
        float s = cg[i*256 + c] * rsqrtf(cv[i*256 + c] + 1e-5f);
        sb[SB_CLS + i*512 + c]       = s;
        sb[SB_CLS + i*512 + 256 + c] = cb[i*256 + c] - cm[i*256 + c] * s;
        float s2 = rg[i*256 + c] * rsqrtf(rv[i*256 + c] + 1e-5f);
        sb[SB_REG + i*512 + c]       = s2;
        sb[SB_REG + i*512 + 256 + c] = rb[i*256 + c] - rm[i*256 + c] * s2;
    }
    float s = btg[c] * rsqrtf(btv[c] + 1e-5f);
    sb[SB_BT + c] = s; sb[SB_BT + 256 + c] = btb[c] - btm[c] * s;
    s = ctg[c] * rsqrtf(ctv[c] + 1e-5f);
    sb[SB_CT + c] = s; sb[SB_CT + 256 + c] = ctb[c] - ctm[c] * s;
}

// ---------------- NCHW f32 -> NHWC bf16 hi/lo planes ----------------
__global__ __launch_bounds__(256) void nchw2nhwc_split(
    const float* __restrict__ in, ushortT* __restrict__ hi, ushortT* __restrict__ lo, int HW)
{
    __shared__ float t[32][33];
    const int b = blockIdx.z, ci0 = blockIdx.y * 32, p0 = blockIdx.x * 32;
    const int tx = threadIdx.x, ty = threadIdx.y;
    for (int i = 0; i < 32; i += 8) {
        int ci = ci0 + ty + i, p = p0 + tx;
        t[ty + i][tx] = (p < HW) ? in[((size_t)(b * 256 + ci)) * HW + p] : 0.0f;
    }
    __syncthreads();
    for (int i = 0; i < 32; i += 8) {
        int p = p0 + ty + i;
        if (p < HW) {
            float v = t[tx][ty + i];
            ushortT h = f2bf(v);
            ushortT l = f2bf(v - bf2f(h));
            size_t o = ((size_t)b * HW + p) * 256 + ci0 + tx;
            hi[o] = h; lo[o] = l;
        }
    }
}

// ---------------- NCHW f32 17x17 -> padded 19x19 NHWC bf16 hi/lo (interior only) ----------------
__global__ __launch_bounds__(256) void nchw2nhwc_pad_split(
    const float* __restrict__ in, ushortT* __restrict__ hi, ushortT* __restrict__ lo)
{
    __shared__ float t[32][33];
    const int b = blockIdx.z, ci0 = blockIdx.y * 32, p0 = blockIdx.x * 32;
    const int tx = threadIdx.x, ty = threadIdx.y;
    for (int i = 0; i < 32; i += 8) {
        int ci = ci0 + ty + i, p = p0 + tx;
        t[ty + i][tx] = (p < 289) ? in[((size_t)(b * 256 + ci)) * 289 + p] : 0.0f;
    }
    __syncthreads();
    for (int i = 0; i < 32; i += 8) {
        int p = p0 + ty + i;
        if (p < 289) {
            float v = t[tx][ty + i];
            ushortT h = f2bf(v);
            ushortT l = f2bf(v - bf2f(h));
            int pp = (p / 17 + 1) * 19 + (p % 17 + 1);
            size_t o = ((size_t)b * 361 + pp) * 256 + ci0 + tx;
            hi[o] = h; lo[o] = l;
        }
    }
}

// ---------------- zero padded NHWC buffers ----------------
__global__ __launch_bounds__(256) void zero_pad_k(ushortT* __restrict__ hi, ushortT* __restrict__ lo)
{
    const size_t n16 = (size_t)64 * 361 * 256 / 8;  // uint4 count per plane
    uint4 z; z.x = z.y = z.z = z.w = 0u;
    uint4* h4 = (uint4*)hi; uint4* l4 = (uint4*)lo;
    for (size_t i = blockIdx.x * 256 + threadIdx.x; i < n16; i += (size_t)gridDim.x * 256) {
        h4[i] = z; l4[i] = z;
    }
}

// ---------------- weight transform: [co][ci][9] -> [co][kidx*256+ci] hi/lo ----------------
__global__ __launch_bounds__(256) void wt_split(
    const float* __restrict__ w, ushortT* __restrict__ whi, ushortT* __restrict__ wlo)
{
    const int co = blockIdx.x & 255, conv = blockIdx.x >> 8;
    const float* src = w + ((size_t)conv * 256 + co) * 2304;
    __shared__ float lw[2304];
    const int t = threadIdx.x;
#pragma unroll
    for (int i = 0; i < 9; i++) lw[i * 256 + t] = src[i * 256 + t];
    __syncthreads();
    size_t ob = ((size_t)conv * 256 + co) * 2304;
#pragma unroll
    for (int i = 0; i < 9; i++) {
        float v = lw[t * 9 + i];
        ushortT h = f2bf(v);
        whi[ob + i * 256 + t] = h;
        wlo[ob + i * 256 + t] = f2bf(v - bf2f(h));
    }
}

// ---------------- MFMA implicit-GEMM conv (VALID, dilated) + BN + relu ----------------
// A: in_t NHWC bf16 hi/lo [B][HI][WI][256]; B: wt [co][kidx*256+ci] hi/lo
// out f32 NCHW [B][256][Ho*Wo]. 1D grid = XT*2*64 blocks (XCD-swizzled), block 256 (4 waves).
// Split-bf16: acc += Ahi*Bhi + Ahi*Blo + Alo*Bhi  (near-f32 accuracy).
// T2: 16B-chunk XOR swizzle (source-side pre-swizzle for global_load_lds; XOR on ds_read).
template <int DH, int DW, int Ho, int Wo, int HI, int WI>
__global__ __launch_bounds__(256, 2) void mfma_conv(
    const ushortT* __restrict__ ahi, const ushortT* __restrict__ alo,
    const ushortT* __restrict__ whi, const ushortT* __restrict__ wlo,
    const float* __restrict__ sb, float* __restrict__ out)
{
    constexpr int NPOS = Ho * Wo;
    constexpr int XT = (NPOS + 127) / 128;
    constexpr int NBLK = XT * 2 * 64;
    __shared__ __align__(16) ushortT lds[4][8192];   // planes A_hi,A_lo,B_hi,B_lo: [128 rows][64 k]

    const int t = threadIdx.x, lane = t & 63, wave = t >> 6;

    // XCD-aware bijective swizzle (NBLK % 8 == 0): each XCD gets a contiguous nid range.
    const int id = blockIdx.x;
    const int nid = (id & 7) * (NBLK >> 3) + (id >> 3);
    const int xt = nid % XT;
    const int rem = nid / XT;
    const int cog = rem & 1;
    const int b = rem >> 1;

    const int m0 = xt * 128;
    const int wrow = wave >> 1, wcol = wave & 1;

    // staging: for q in 0..3, row = q*32 + wave*8 + (lane>>3); stored 16B-chunk = lane&7.
    // Source chunk pre-swizzled: g = (lane&7) ^ (row&7), row&7 == lane>>3 here.
    const int lrow = lane >> 3;
    const int e8 = (((lane & 7) ^ lrow) & 7) * 8;
    int aoh[4], aow[4];
    size_t wrb[4];
#pragma unroll
    for (int q = 0; q < 4; q++) {
        int r = q * 32 + wave * 8 + lrow;
        int p = m0 + r; if (p > NPOS - 1) p = NPOS - 1;
        aoh[q] = p / Wo; aow[q] = p - aoh[q] * Wo;
        wrb[q] = (size_t)(cog * 128 + r) * 2304 + e8;
    }

    f32x4 acc[4][4];
#pragma unroll
    for (int i = 0; i < 4; i++)
#pragma unroll
        for (int j = 0; j < 4; j++) acc[i][j] = (f32x4){0.f, 0.f, 0.f, 0.f};

    const int arow = lane & 15;
    const int sw = arow & 7;                 // read-side XOR (row&7, constant across mt/nt)
    const int lsel = lane >> 4;              // k sub-run selector

#pragma unroll 1
    for (int kidx = 0; kidx < 9; ++kidx) {
        const int kh = kidx / 3, kw = kidx - kh * 3;
        size_t ab[4];
#pragma unroll
        for (int q = 0; q < 4; q++)
            ab[q] = ((size_t)((b * HI) + aoh[q] + DH * kh) * WI + aow[q] + DW * kw) * 256 + e8;
        const size_t wk = (size_t)kidx * 256;
#pragma unroll 1
        for (int s = 0; s < 4; ++s) {
            const int cs = s * 64;
#pragma unroll
            for (int q = 0; q < 4; q++) {
                const int dst = (q * 32 + wave * 8) * 64;   // wave-uniform; HW adds lane*16B
                gl16(ahi + ab[q] + cs, &lds[0][dst]);
                gl16(alo + ab[q] + cs, &lds[1][dst]);
                gl16(whi + wrb[q] + wk + cs, &lds[2][dst]);
                gl16(wlo + wrb[q] + wk + cs, &lds[3][dst]);
            }
            __syncthreads();
#pragma unroll
            for (int kk = 0; kk < 2; ++kk) {
                const int koS = (((kk * 4 + lsel) ^ sw) << 3);   // swizzled chunk
                bf8 ah[4], al[4], bh[4], bl[4];
#pragma unroll
                for (int mt = 0; mt < 4; ++mt) {
                    int r = wrow * 64 + mt * 16 + arow;
                    ah[mt] = *(const bf8*)&lds[0][r * 64 + koS];
                    al[mt] = *(const bf8*)&lds[1][r * 64 + koS];
                }
#pragma unroll
                for (int nt = 0; nt < 4; ++nt) {
                    int r = wcol * 64 + nt * 16 + arow;
                    bh[nt] = *(const bf8*)&lds[2][r * 64 + koS];
                    bl[nt] = *(const bf8*)&lds[3][r * 64 + koS];
                }
#pragma unroll
                for (int mt = 0; mt < 4; ++mt)
#pragma unroll
                    for (int nt = 0; nt < 4; ++nt) {
                        acc[mt][nt] = __builtin_amdgcn_mfma_f32_16x16x32_bf16(ah[mt], bh[nt], acc[mt][nt], 0, 0, 0);
                        acc[mt][nt] = __builtin_amdgcn_mfma_f32_16x16x32_bf16(ah[mt], bl[nt], acc[mt][nt], 0, 0, 0);
                        acc[mt][nt] = __builtin_amdgcn_mfma_f32_16x16x32_bf16(al[mt], bh[nt], acc[mt][nt], 0, 0, 0);
                    }
            }
            __syncthreads();
        }
    }

    // epilogue: folded BN + relu, f32 NCHW store
#pragma unroll
    for (int nt = 0; nt < 4; ++nt) {
        const int co = cog * 128 + wcol * 64 + nt * 16 + arow;
        const float scl = sb[co], bia = sb[256 + co];
        const size_t ob = ((size_t)b * 256 + co) * NPOS;
#pragma unroll
        for (int mt = 0; mt < 4; ++mt)
#pragma unroll
            for (int r = 0; r < 4; ++r) {
                int p = m0 + wrow * 64 + mt * 16 + (lane >> 4) * 4 + r;
                if (p < NPOS) {
                    float v = fmaf(acc[mt][nt][r], scl, bia);
                    out[ob + p] = v > 0.f ? v : 0.f;
                }
            }
    }
}

// ---------------- depthwise xcorr (one of 3), softmax-weighted accumulate ----------------
template <int HZ_, int WZ_, int WX_, int IDX>
__global__ __launch_bounds__(192) void xcorr_one(
    const float* __restrict__ z, const float* __restrict__ x,
    const float* __restrict__ w3, float* __restrict__ out)
{
    constexpr int HX_ = 16 + HZ_;
    constexpr int NX = HX_ * WX_;
    constexpr int NZ = HZ_ * WZ_;
    __shared__ float xs[NX + 4];
    __shared__ float zs[NZ];
    const int bc = blockIdx.x;
    const float* xp = x + (size_t)bc * NX;
    const float* zp = z + (size_t)bc * NZ;
    for (int i = threadIdx.x; i < NX; i += 192) xs[i] = xp[i];
    for (int i = threadIdx.x; i < NZ; i += 192) zs[i] = zp[i];

    float a = w3[0], b = w3[1], c = w3[2];
    float mx = fmaxf(a, fmaxf(b, c));
    float e0 = expf(a - mx), e1 = expf(b - mx), e2 = expf(c - mx);
    float wt = (IDX == 0 ? e0 : (IDX == 1 ? e1 : e2)) / (e0 + e1 + e2);
    __syncthreads();

    int t = threadIdx.x;
    if (t >= 153) return;
    int oh = t / 9, owp = t % 9, ow0 = owp * 2;
    float s0 = 0.0f, s1 = 0.0f;
#pragma unroll 1
    for (int kh = 0; kh < HZ_; kh++) {
        const float* xr = &xs[(oh + kh) * WX_ + ow0];
        const float* zr = &zs[kh * WZ_];
#pragma unroll
        for (int kw = 0; kw < WZ_; kw++) {
            float zv = zr[kw];
            s0 = fmaf(xr[kw], zv, s0);
            s1 = fmaf(xr[kw + 1], zv, s1);
        }
    }
    size_t o = (size_t)bc * 289 + oh * 17 + ow0;
    if (IDX == 0) {
        out[o] = wt * s0;
        if (owp < 8) out[o + 1] = wt * s1;
    } else {
        out[o] += wt * s0;
        if (owp < 8) out[o + 1] += wt * s1;
    }
}

// ---------------- bbox pred ----------------
__global__ __launch_bounds__(320) void bp_pred(
    const float* __restrict__ xr, const float* __restrict__ w,
    const float* __restrict__ wb, const float* __restrict__ adj,
    const float* __restrict__ bia, float* __restrict__ outx)
{
    int b = blockIdx.x;
    int p = threadIdx.x;
    if (p >= 289) return;
    int oh = p / 17, ow = p % 17;
    float acc[4] = {0.f, 0.f, 0.f, 0.f};
    const float* xb = xr + (size_t)b * 256 * 289;
#pragma unroll 1
    for (int cin = 0; cin < 256; cin++) {
        const float* ip = xb + (size_t)cin * 289;
#pragma unroll
        for (int kh = 0; kh < 3; kh++) {
            int ih = oh - 1 + kh;
            bool okh = (unsigned)ih < 17u;
            int ihc = okh ? ih : 0;
#pragma unroll
            for (int kw = 0; kw < 3; kw++) {
                int iw = ow - 1 + kw;
                bool ok = okh && ((unsigned)iw < 17u);
                int iwc = ok ? iw : 0;
                float v = ip[ihc * 17 + iwc];
                v = ok ? v : 0.0f;
#pragma unroll
                for (int co = 0; co < 4; co++)
                    acc[co] = fmaf(v, w[(size_t)(co * 256 + cin) * 9 + kh * 3 + kw], acc[co]);
            }
        }
    }
    float ad = adj[0];
#pragma unroll
    for (int co = 0; co < 4; co++) {
        float t2 = fmaf(ad, acc[co] + wb[co], bia[co]);
        outx[((size_t)b * 4 + co) * 289 + p] = expf(fminf(t2, 4.7f));
    }
}

// ---------------- cls pred ----------------
__global__ __launch_bounds__(320) void cp_pred(
    const float* __restrict__ cfeat, const float* __restrict__ w,
    const float* __restrict__ wb, float* __restrict__ outc)
{
    int b = blockIdx.x;
    int p = threadIdx.x;
    if (p >= 289) return;
    int oh = p / 17, ow = p % 17;
    float acc = 0.f;
#pragma unroll 1
    for (int cin = 0; cin < 256; cin++) {
        const float* ip = cfeat + ((size_t)b * 256 + cin) * 289;
#pragma unroll
        for (int kh = 0; kh < 3; kh++) {
            int ih = oh - 1 + kh;
            bool okh = (unsigned)ih < 17u;
            int ihc = okh ? ih : 0;
#pragma unroll
            for (int kw = 0; kw < 3; kw++) {
                int iw = ow - 1 + kw;
                bool ok = okh && ((unsigned)iw < 17u);
                int iwc = ok ? iw : 0;
                float v = ip[ihc * 17 + iwc];
                v = ok ? v : 0.0f;
                acc = fmaf(v, w[(size_t)cin * 9 + kh * 3 + kw], acc);
            }
        }
    }
    outc[(size_t)b * 289 + p] = 0.1f * (acc + wb[0]);
}

// ---------------- host launch ----------------
extern "C" void kernel_launch(void* const* d_in, const int* in_sizes, int n_in,
                              void* d_out, int out_size, void* d_ws, size_t ws_size,
                              hipStream_t stream)
{
    (void)in_sizes; (void)n_in; (void)out_size; (void)ws_size;
    const float* search = (const float*)d_in[0];
    const float* kern   = (const float*)d_in[1];
    const float* cls_mw = (const float*)d_in[2];
    const float* reg_mw = (const float*)d_in[7];
    const float* cls_dww = (const float*)d_in[12];
    const float* reg_dww = (const float*)d_in[13];
    const float* btw = (const float*)d_in[14];
    const float* ctw = (const float*)d_in[19];
    const float* bpw = (const float*)d_in[24];
    const float* bpb = (const float*)d_in[25];
    const float* cpw = (const float*)d_in[26];
    const float* cpb = (const float*)d_in[27];
    const float* adj = (const float*)d_in[28];
    const float* bia = (const float*)d_in[29];

    float* ws  = (float*)d_ws;
    float* out = (float*)d_out;

    ushortT* wt_hi = (ushortT*)(ws + WT_HI);
    ushortT* wt_lo = (ushortT*)(ws + WT_LO);
    ushortT* s_hi  = (ushortT*)(ws + INT_SH);
    ushortT* s_lo  = (ushortT*)(ws + INT_SL);
    ushortT* z_hi  = (ushortT*)(ws + INT_ZH);
    ushortT* z_lo  = (ushortT*)(ws + INT_ZL);
    // tower-phase aliases (search NHWC + wt regions dead by then)
    ushortT* pad_hi = s_hi;
    ushortT* pad_lo = s_lo;

    fold_bn_k<<<1, 256, 0, stream>>>(
        (const float*)d_in[3], (const float*)d_in[4], (const float*)d_in[5], (const float*)d_in[6],
        (const float*)d_in[8], (const float*)d_in[9], (const float*)d_in[10], (const float*)d_in[11],
        (const float*)d_in[15], (const float*)d_in[16], (const float*)d_in[17], (const float*)d_in[18],
        (const float*)d_in[20], (const float*)d_in[21], (const float*)d_in[22], (const float*)d_in[23],
        ws);

    // input transforms (shared across both branches)
    nchw2nhwc_split<<<dim3(31, 8, 64), dim3(32, 8), 0, stream>>>(search, s_hi, s_lo, 961);
    nchw2nhwc_split<<<dim3(8, 8, 64), dim3(32, 8), 0, stream>>>(kern, z_hi, z_lo, 225);

    const size_t WC = (size_t)2304 * 256; // per-conv wt plane stride (ushorts)

    auto branch = [&](const float* mw, const float* sbb, const float* dww, float* dwout) {
        wt_split<<<1536, 256, 0, stream>>>(mw, wt_hi, wt_lo);
        // pair 0: dil (1,1): z 13x13, x 29x29
        mfma_conv<1, 1, 13, 13, 15, 15><<<256, 256, 0, stream>>>(
            z_hi, z_lo, wt_hi + 0 * WC, wt_lo + 0 * WC, sbb + 0 * 512, ws + WS_ZB);
        mfma_conv<1, 1, 29, 29, 31, 31><<<896, 256, 0, stream>>>(
            s_hi, s_lo, wt_hi + 1 * WC, wt_lo + 1 * WC, sbb + 1 * 512, ws + WS_XB);
        xcorr_one<13, 13, 29, 0><<<16384, 192, 0, stream>>>(ws + WS_ZB, ws + WS_XB, dww, dwout);
        // pair 1: dil (2,1): z 11x13, x 27x29
        mfma_conv<2, 1, 11, 13, 15, 15><<<256, 256, 0, stream>>>(
            z_hi, z_lo, wt_hi + 2 * WC, wt_lo + 2 * WC, sbb + 2 * 512, ws + WS_ZB);
        mfma_conv<2, 1, 27, 29, 31, 31><<<896, 256, 0, stream>>>(
            s_hi, s_lo, wt_hi + 3 * WC, wt_lo + 3 * WC, sbb + 3 * 512, ws + WS_XB);
        xcorr_one<11, 13, 29, 1><<<16384, 192, 0, stream>>>(ws + WS_ZB, ws + WS_XB, dww, dwout);
        // pair 2: dil (1,2): z 13x11, x 29x27
        mfma_conv<1, 2, 13, 11, 15, 15><<<256, 256, 0, stream>>>(
            z_hi, z_lo, wt_hi + 4 * WC, wt_lo + 4 * WC, sbb + 4 * 512, ws + WS_ZB);
        mfma_conv<1, 2, 29, 27, 31, 31><<<896, 256, 0, stream>>>(
            s_hi, s_lo, wt_hi + 5 * WC, wt_lo + 5 * WC, sbb + 5 * 512, ws + WS_XB);
        xcorr_one<13, 11, 27, 2><<<16384, 192, 0, stream>>>(ws + WS_ZB, ws + WS_XB, dww, dwout);
    };

    // cls branch -> cls_dw directly in d_out; reg branch -> ws
    branch(cls_mw, ws + SB_CLS, cls_dww, out + O_CDW);
    branch(reg_mw, ws + SB_REG, reg_dww, ws + WS_RDW);

    // ---- towers (MFMA path): search NHWC + wt regions now dead, reuse them ----
    wt_split<<<256, 256, 0, stream>>>(btw, wt_hi, wt_lo);                 // slot 0 = bt
    wt_split<<<256, 256, 0, stream>>>(ctw, wt_hi + WC, wt_lo + WC);       // slot 1 = ct
    zero_pad_k<<<1024, 256, 0, stream>>>(pad_hi, pad_lo);

    // bbox tower: pad(reg_dw) -> mfma conv -> x_reg (d_out), then bp conv + exp -> x (d_out)
    nchw2nhwc_pad_split<<<dim3(10, 8, 64), dim3(32, 8), 0, stream>>>(ws + WS_RDW, pad_hi, pad_lo);
    mfma_conv<1, 1, 17, 17, 19, 19><<<384, 256, 0, stream>>>(
        pad_hi, pad_lo, wt_hi, wt_lo, ws + SB_BT, out + O_XREG);
    bp_pred<<<64, 320, 0, stream>>>(out + O_XREG, bpw, bpb, adj, bia, out + O_X);

    // cls tower: pad(cls_dw) -> mfma conv -> c (ws), then cp conv -> cls (d_out)
    // (border zeros persist from zero_pad_k; interior fully rewritten)
    nchw2nhwc_pad_split<<<dim3(10, 8, 64), dim3(32, 8), 0, stream>>>(out + O_CDW, pad_hi, pad_lo);
    mfma_conv<1, 1, 17, 17, 19, 19><<<384, 256, 0, stream>>>(
        pad_hi, pad_lo, wt_hi + WC, wt_lo + WC, ws + SB_CT, ws + WS_CB);
    cp_pred<<<64, 320, 0, stream>>>(ws + WS_CB, cpw, cpb, out + O_CLS);
}